// Round 2
// baseline (489.546 us; speedup 1.0000x reference)
//
#include <hip/hip_runtime.h>
#include <hip/hip_bf16.h>

// GroupedMLP: E=8, H=1024, I=2816, T=8192. ALL tensors fp32 in HBM (per reference);
// compute in bf16 MFMA with fp32 accumulate (threshold 0.0403 >> predicted 0.01).
// Pipeline:
//   0) convx:  X fp32 -> xb bf16  (staged inside d_out; gemm3 overwrites it later)
//   1) tconv gate [E,H,I] fp32 -> gateT bf16 [E,I,H]   (K-fastest B^T layout)
//   2) tconv up   -> upT bf16
//   3) gemm12: inter = silu(xb@gate) * (xb@up), bf16, m97-style MFMA tiles
//   4) tconv down [E,I,H] fp32 -> downT bf16 [E,H,I]   (reuses gateT region)
//   5) gemm3: out = inter @ down -> fp32 d_out (m97-exact 128x128 tile)
// Workspace: 3 x 46,137,344 B = 138,412,032 B (round-1 evidence: ws >= this).

#define E_ 8
#define H_ 1024
#define I_ 2816
#define T_ 8192

typedef unsigned short u16;
typedef __attribute__((ext_vector_type(8))) short s16x8;     // 8 bf16 MFMA frag (4 VGPRs)
typedef __attribute__((ext_vector_type(8))) unsigned short u16x8;
typedef __attribute__((ext_vector_type(4))) float f32x4;     // MFMA C/D frag

__device__ __forceinline__ void async16(const u16* g, u16* l) {
  // global -> LDS direct DMA, 16 B/lane. LDS dest = wave-uniform base + lane*16.
  __builtin_amdgcn_global_load_lds((__attribute__((address_space(1))) void*)g,
                                   (__attribute__((address_space(3))) void*)l, 16, 0, 0);
}

__device__ __forceinline__ u16 f2b(float f) {
  union { __hip_bfloat16 h; u16 u; } c;
  c.h = __float2bfloat16(f);
  return c.u;
}

// ---------------- convert X fp32 -> bf16, 8 elems/thread ----------------
__global__ __launch_bounds__(256) void convx_k(const float* __restrict__ x,
                                               u16* __restrict__ xb) {
  size_t i = ((size_t)blockIdx.x * 256 + threadIdx.x) * 8;
  float4 v0 = *(const float4*)(x + i);
  float4 v1 = *(const float4*)(x + i + 4);
  u16x8 b;
  b[0] = f2b(v0.x); b[1] = f2b(v0.y); b[2] = f2b(v0.z); b[3] = f2b(v0.w);
  b[4] = f2b(v1.x); b[5] = f2b(v1.y); b[6] = f2b(v1.z); b[7] = f2b(v1.w);
  *(u16x8*)(xb + i) = b;
}

// ------- transpose+convert: out[C][R] (bf16) = in[R][C] (fp32), expert = blockIdx.z -------
__global__ __launch_bounds__(256) void tconv_k(const float* __restrict__ in,
                                               u16* __restrict__ out,
                                               int R, int C) {
  __shared__ u16 tile[64][72];  // stride 72 u16 = 144 B keeps 16B alignment
  const int t = threadIdx.x;
  const size_t eoff = (size_t)blockIdx.z * (size_t)R * (size_t)C;
  in += eoff; out += eoff;
  const int c0 = blockIdx.x * 64, r0 = blockIdx.y * 64;
#pragma unroll
  for (int h = 0; h < 2; ++h) {
    int r = h * 32 + (t >> 3);
    int c8 = (t & 7) * 8;
    const float* p = in + (size_t)(r0 + r) * C + c0 + c8;
    float4 v0 = *(const float4*)p;
    float4 v1 = *(const float4*)(p + 4);
    u16x8 b;
    b[0] = f2b(v0.x); b[1] = f2b(v0.y); b[2] = f2b(v0.z); b[3] = f2b(v0.w);
    b[4] = f2b(v1.x); b[5] = f2b(v1.y); b[6] = f2b(v1.z); b[7] = f2b(v1.w);
    *(u16x8*)&tile[r][c8] = b;
  }
  __syncthreads();
#pragma unroll
  for (int h = 0; h < 2; ++h) {
    int c = h * 32 + (t >> 3);
    int r8 = (t & 7) * 8;
    u16x8 v;
#pragma unroll
    for (int j = 0; j < 8; ++j) v[j] = tile[r8 + j][c];
    *(u16x8*)(out + (size_t)(c0 + c) * R + r0 + r8) = v;
  }
}

// ---------------- fused gate/up GEMM + SwiGLU ----------------
// C tile: BM=128 tokens x BN=64 (of I), two outputs (gate,up) -> inter bf16.
// 4 waves, each 64(M)x32(N) per output: acc 4x2 f32x4 per output.
__global__ __launch_bounds__(256, 2) void gemm12_k(
    const u16* __restrict__ X, const u16* __restrict__ GT,
    const u16* __restrict__ UT, const int* __restrict__ tpe,
    u16* __restrict__ inter) {
  __shared__ u16 sA[128 * 32];  // [m][k] k-fastest
  __shared__ u16 sG[64 * 32];   // [n][k] k-fastest (weights pre-transposed)
  __shared__ u16 sU[64 * 32];
  const int t = threadIdx.x;
  const int m0 = blockIdx.y * 128;
  const int n0 = blockIdx.x * 64;

  int e = 0, seg_end = T_;
  {
    int s = 0;
    for (int i = 0; i < E_; ++i) {
      int c = tpe[i];
      if (m0 < s + c) { e = i; seg_end = s + c; break; }
      s += c;
    }
  }
  const u16* GTe = GT + (size_t)e * I_ * H_;
  const u16* UTe = UT + (size_t)e * I_ * H_;

  const u16* gA0 = X + (size_t)(m0 + (t >> 2)) * H_ + (t & 3) * 8;
  const u16* gA1 = gA0 + (size_t)64 * H_;
  const u16* gG  = GTe + (size_t)(n0 + (t >> 2)) * H_ + (t & 3) * 8;
  const u16* gU  = UTe + (size_t)(n0 + (t >> 2)) * H_ + (t & 3) * 8;
  u16* lA = sA + t * 8;
  u16* lG = sG + t * 8;
  u16* lU = sU + t * 8;

  const int l = t & 63, w = t >> 6;
  const int wm = (w & 1) * 64, wn = (w >> 1) * 32;
  const u16* fA = sA + (size_t)(wm + (l & 15)) * 32 + (l >> 4) * 8;
  const u16* fG = sG + (size_t)(wn + (l & 15)) * 32 + (l >> 4) * 8;
  const u16* fU = sU + (size_t)(wn + (l & 15)) * 32 + (l >> 4) * 8;

  f32x4 accG[4][2], accU[4][2];
#pragma unroll
  for (int mi = 0; mi < 4; ++mi)
#pragma unroll
    for (int ni = 0; ni < 2; ++ni) {
      accG[mi][ni] = (f32x4){0.f, 0.f, 0.f, 0.f};
      accU[mi][ni] = (f32x4){0.f, 0.f, 0.f, 0.f};
    }

  for (int k0 = 0; k0 < H_; k0 += 32) {
    async16(gA0 + k0, lA);
    async16(gA1 + k0, lA + 2048);
    async16(gG + k0, lG);
    async16(gU + k0, lU);
    __syncthreads();
    s16x8 aF[4], gF[2], uF[2];
#pragma unroll
    for (int mi = 0; mi < 4; ++mi) aF[mi] = *(const s16x8*)(fA + mi * 512);
#pragma unroll
    for (int ni = 0; ni < 2; ++ni) {
      gF[ni] = *(const s16x8*)(fG + ni * 512);
      uF[ni] = *(const s16x8*)(fU + ni * 512);
    }
#pragma unroll
    for (int mi = 0; mi < 4; ++mi)
#pragma unroll
      for (int ni = 0; ni < 2; ++ni) {
        accG[mi][ni] = __builtin_amdgcn_mfma_f32_16x16x32_bf16(aF[mi], gF[ni], accG[mi][ni], 0, 0, 0);
        accU[mi][ni] = __builtin_amdgcn_mfma_f32_16x16x32_bf16(aF[mi], uF[ni], accU[mi][ni], 0, 0, 0);
      }
    __syncthreads();
  }

  // epilogue: C/D layout col=lane&15, row=(lane>>4)*4+reg
  const int colb = l & 15, rowb = (l >> 4) * 4;
#pragma unroll
  for (int mi = 0; mi < 4; ++mi)
#pragma unroll
    for (int ni = 0; ni < 2; ++ni) {
      const size_t gcol = (size_t)(n0 + wn + ni * 16 + colb);
#pragma unroll
      for (int r = 0; r < 4; ++r) {
        int grow = m0 + wm + mi * 16 + rowb + r;
        if (grow < seg_end) {
          float o1 = accG[mi][ni][r];
          float o2 = accU[mi][ni][r];
          float sv = o1 / (1.f + __expf(-o1));  // silu
          inter[(size_t)grow * I_ + gcol] = f2b(sv * o2);
        }
      }
    }
}

// ---------------- down-proj GEMM (m97-exact 128x128 tile), fp32 out ----------------
__global__ __launch_bounds__(256, 2) void gemm3_k(
    const u16* __restrict__ A, const u16* __restrict__ DT,
    const int* __restrict__ tpe, float* __restrict__ out) {
  __shared__ u16 sA[128 * 32];
  __shared__ u16 sB[128 * 32];
  const int t = threadIdx.x;
  const int m0 = blockIdx.y * 128;
  const int n0 = blockIdx.x * 128;

  int e = 0, seg_end = T_;
  {
    int s = 0;
    for (int i = 0; i < E_; ++i) {
      int c = tpe[i];
      if (m0 < s + c) { e = i; seg_end = s + c; break; }
      s += c;
    }
  }
  const u16* DTe = DT + (size_t)e * H_ * I_;

  const u16* gA0 = A + (size_t)(m0 + (t >> 2)) * I_ + (t & 3) * 8;
  const u16* gA1 = gA0 + (size_t)64 * I_;
  const u16* gB0 = DTe + (size_t)(n0 + (t >> 2)) * I_ + (t & 3) * 8;
  const u16* gB1 = gB0 + (size_t)64 * I_;
  u16* lA = sA + t * 8;
  u16* lB = sB + t * 8;

  const int l = t & 63, w = t >> 6;
  const int wm = (w & 1) * 64, wn = (w >> 1) * 64;
  const u16* fA = sA + (size_t)(wm + (l & 15)) * 32 + (l >> 4) * 8;
  const u16* fB = sB + (size_t)(wn + (l & 15)) * 32 + (l >> 4) * 8;

  f32x4 acc[4][4];
#pragma unroll
  for (int mi = 0; mi < 4; ++mi)
#pragma unroll
    for (int ni = 0; ni < 4; ++ni) acc[mi][ni] = (f32x4){0.f, 0.f, 0.f, 0.f};

  for (int k0 = 0; k0 < I_; k0 += 32) {
    async16(gA0 + k0, lA);
    async16(gA1 + k0, lA + 2048);
    async16(gB0 + k0, lB);
    async16(gB1 + k0, lB + 2048);
    __syncthreads();
    s16x8 aF[4], bF[4];
#pragma unroll
    for (int mi = 0; mi < 4; ++mi) aF[mi] = *(const s16x8*)(fA + mi * 512);
#pragma unroll
    for (int ni = 0; ni < 4; ++ni) bF[ni] = *(const s16x8*)(fB + ni * 512);
#pragma unroll
    for (int mi = 0; mi < 4; ++mi)
#pragma unroll
      for (int ni = 0; ni < 4; ++ni)
        acc[mi][ni] = __builtin_amdgcn_mfma_f32_16x16x32_bf16(aF[mi], bF[ni], acc[mi][ni], 0, 0, 0);
    __syncthreads();
  }

  const int colb = l & 15, rowb = (l >> 4) * 4;
#pragma unroll
  for (int mi = 0; mi < 4; ++mi)
#pragma unroll
    for (int ni = 0; ni < 4; ++ni) {
      const size_t gcol = (size_t)(n0 + wn + ni * 16 + colb);
#pragma unroll
      for (int r = 0; r < 4; ++r) {
        int grow = m0 + wm + mi * 16 + rowb + r;
        if (grow < seg_end) out[(size_t)grow * H_ + gcol] = acc[mi][ni][r];
      }
    }
}

extern "C" void kernel_launch(void* const* d_in, const int* in_sizes, int n_in,
                              void* d_out, int out_size, void* d_ws, size_t ws_size,
                              hipStream_t stream) {
  const float* X = (const float*)d_in[0];
  const float* G = (const float*)d_in[1];
  const float* U = (const float*)d_in[2];
  const float* D = (const float*)d_in[3];
  const int* tpe = (const int*)d_in[4];
  float* out = (float*)d_out;

  const size_t W = (size_t)E_ * H_ * I_;  // 23,068,672 elems (== T_*I_)
  if (ws_size < 3 * W * sizeof(u16)) return;  // 138,412,032 B (round 1: satisfied)
  u16* r0 = (u16*)d_ws;   // gateT, later downT
  u16* r1 = r0 + W;       // upT
  u16* r2 = r1 + W;       // inter [T][I] bf16
  u16* xb = (u16*)d_out;  // bf16 X staged in d_out (16 MB of 32 MB); gemm3 overwrites

  convx_k<<<dim3((T_ * H_) / (256 * 8)), 256, 0, stream>>>(X, xb);
  tconv_k<<<dim3(I_ / 64, H_ / 64, E_), 256, 0, stream>>>(G, r0, H_, I_);
  tconv_k<<<dim3(I_ / 64, H_ / 64, E_), 256, 0, stream>>>(U, r1, H_, I_);
  gemm12_k<<<dim3(I_ / 64, T_ / 128), 256, 0, stream>>>(xb, r0, r1, tpe, r2);
  tconv_k<<<dim3(H_ / 64, I_ / 64, E_), 256, 0, stream>>>(D, r0, I_, H_);
  gemm3_k<<<dim3(H_ / 128, T_ / 128), 256, 0, stream>>>(r2, r0, tpe, out);
}